// Round 15
// baseline (147.726 us; speedup 1.0000x reference)
//
#include <hip/hip_runtime.h>
#include <hip/hip_bf16.h>
#include <stdint.h>

// ============================================================================
// AdaptiveEdgeDropping: out = matrix with top-k (k = E*pct/100) of
// (log_sigmoid(dp*(1-v) - g*v) + gumbel(key=42)) zeroed.  BIT-EXACT.
//
// Round 15: hybrid of proven pieces.
//  - Stream + find_verify: R14 (UNFUSED — R13 showed a per-block threadfence
//    in the 68MB-dirty stream costs ~240us; never fence the big kernel).
//    q2-space base-2 math: key >= t <=> q2 <= e^{-t}*log2e,
//    q2 = fma(w2, e2, w2), w2 = -v_log_f32(u), e2 = v_exp_f32(A2*v - dp2).
//  - Tail: R13's last-block-fused kernels (sample+find_sample,
//    exact_eval+find_band, band_drop+ties) — small dirty footprints, fence
//    cheap; aload (agent-scope atomic loads) for cross-block reads (the
//    R12->R13 replay-safety fix; R13 passed pre+post validation).
//  11 dispatches -> 7.
// ============================================================================

#define NBINS 8192
#define NBINS_SHIFT 19            // approx code >> 19 -> 13-bit bin
#define NBS 64                    // sample blocks (x1024 thr)
#define NBSTREAM 1024             // stream blocks  (R8/R10/R14-proven shape)
#define STREAM_T 512              // stream threads/block
#define NB2 128                   // exact_eval blocks
#define NB3 64                    // band_drop blocks
#define LIST_CAP 2097152u
#define MINI_CAP 16384u
#define LBUF_CAP 2048
#define TIES_TILE 2048
#define SLACK 2
#define MARGIN 2.0e-4f
#define LOG2E 1.44269504088896340736f

// ---------------- device-coherent load (cross-block, intra-kernel) ----------
__device__ __forceinline__ unsigned aload(const unsigned* p) {
  return __hip_atomic_load(p, __ATOMIC_RELAXED, __HIP_MEMORY_SCOPE_AGENT);
}

// ---------------- threefry2x32, key=(0,42), counts=(0,i), out = x0^x1 -------
__device__ __forceinline__ unsigned tf_bits(unsigned i) {
  const unsigned ks0 = 0u;
  const unsigned ks1 = 42u;
  const unsigned ks2 = 0x1BD11BDAu ^ 0u ^ 42u;
  unsigned x0 = 0u + ks0;
  unsigned x1 = i + ks1;
#define TF_R(rot) { x0 += x1; \
  x1 = __builtin_amdgcn_alignbit(x1, x1, 32u - (rot)); x1 ^= x0; }
  TF_R(13) TF_R(15) TF_R(26) TF_R(6)
  x0 += ks1; x1 += ks2 + 1u;
  TF_R(17) TF_R(29) TF_R(16) TF_R(24)
  x0 += ks2; x1 += ks0 + 2u;
  TF_R(13) TF_R(15) TF_R(26) TF_R(6)
  x0 += ks0; x1 += ks1 + 3u;
  TF_R(17) TF_R(29) TF_R(16) TF_R(24)
  x0 += ks1; x1 += ks2 + 4u;
  TF_R(13) TF_R(15) TF_R(26) TF_R(6)
  x0 += ks2; x1 += ks0 + 5u;
#undef TF_R
  return x0 ^ x1;
}

// ---------------- jax.random.uniform(minval=1e-7, maxval=1-1e-7) -----------
__device__ __forceinline__ float uniform_from_bits(unsigned bits) {
  unsigned fb = (bits >> 9) | 0x3f800000u;
  float f = __uint_as_float(fb) - 1.0f;
  const float minv = 1e-7f;
  const float maxv = __uint_as_float(0x3F7FFFFEu);   // f32(1.0 - 1e-7)
  float r = __fsub_rn(maxv, minv);
  float u = __fadd_rn(__fmul_rn(f, r), minv);
  return fmaxf(minv, u);
}

// ---------------- XLA-CPU Cephes expf (unfused) ----------------------------
__device__ __forceinline__ float xla_expf(float input) {
  const float exp_hi = 88.3762626647950f;
  const float exp_lo = -88.3762626647949f;
  float x = fminf(fmaxf(input, exp_lo), exp_hi);
  float fx = floorf(__fadd_rn(__fmul_rn(x, 1.44269504088896341f), 0.5f));
  float tmp = __fmul_rn(0.693359375f, fx);
  float z = __fmul_rn(-2.12194440e-4f, fx);
  x = __fsub_rn(x, tmp);
  x = __fsub_rn(x, z);
  z = __fmul_rn(x, x);
  float y = __fadd_rn(__fmul_rn(x, 1.9875691500e-4f), 1.3981999507e-3f);
  y = __fadd_rn(__fmul_rn(y, x), 8.3334519073e-3f);
  y = __fadd_rn(__fmul_rn(y, x), 4.1665795894e-2f);
  y = __fadd_rn(__fmul_rn(y, x), 1.6666665459e-1f);
  y = __fadd_rn(__fmul_rn(y, x), 5.0000001201e-1f);
  y = __fadd_rn(__fmul_rn(y, z), x);
  y = __fadd_rn(1.0f, y);
  int n = (int)fx;
  float p2n = __int_as_float((n + 0x7f) << 23);
  return fmaxf(__fmul_rn(y, p2n), input);
}

// ---------------- XLA-CPU Cephes logf (Estrin, unfused) --------------------
__device__ __forceinline__ float xla_logf(float input) {
  float t0 = fmaxf(input, __uint_as_float(0x00800000u));
  unsigned ib = __float_as_uint(t0);
  int emm0 = (int)(ib >> 23) - 0x7f;
  float e = __fadd_rn(1.0f, (float)emm0);
  float m = __uint_as_float((ib & 0x807fffffu) | 0x3f000000u);
  bool mask = m < 0.707106781186547524f;
  float t1 = mask ? m : 0.0f;
  m = __fsub_rn(m, 1.0f);
  e = __fsub_rn(e, mask ? 1.0f : 0.0f);
  m = __fadd_rn(m, t1);
  float x2 = __fmul_rn(m, m);
  float x3 = __fmul_rn(x2, m);
  float y  = __fadd_rn(__fmul_rn(m, 7.0376836292e-2f), -1.1514610310e-1f);
  float y1 = __fadd_rn(__fmul_rn(m, -1.2420140846e-1f), 1.4249322787e-1f);
  float y2 = __fadd_rn(__fmul_rn(m, 2.0000714765e-1f), -2.4999993993e-1f);
  y  = __fadd_rn(__fmul_rn(y, m), 1.1676998740e-1f);
  y1 = __fadd_rn(__fmul_rn(y1, m), -1.6668057665e-1f);
  y2 = __fadd_rn(__fmul_rn(y2, m), 3.3333331174e-1f);
  y = __fadd_rn(__fmul_rn(y, x3), y1);
  y = __fadd_rn(__fmul_rn(y, x3), y2);
  y = __fmul_rn(y, x3);
  y = __fadd_rn(y, __fmul_rn(-2.12194440e-4f, e));
  y = __fsub_rn(y, __fmul_rn(0.5f, x2));
  m = __fadd_rn(m, y);
  m = __fadd_rn(m, __fmul_rn(0.693359375f, e));
  return m;
}

// ---------------- XLA elemental log1p --------------------------------------
__device__ __forceinline__ float xla_log1pf(float x) {
  float for_large = xla_logf(__fadd_rn(x, 1.0f));
  float for_small = __fmul_rn(__fadd_rn(__fmul_rn(-0.5f, x), 1.0f), x);
  return (fabsf(x) < 1e-4f) ? for_small : for_large;
}

// ---------------- monotone code <-> float ----------------------------------
__device__ __forceinline__ unsigned encode_f(float f) {
  unsigned b = __float_as_uint(f);
  return (b & 0x80000000u) ? ~b : (b | 0x80000000u);
}
__device__ __forceinline__ float decode_f(unsigned c) {
  unsigned b = (c & 0x80000000u) ? (c ^ 0x80000000u) : ~c;
  return __uint_as_float(b);
}

// ---------------- EXACT per-element key code (verified bit-exact) ----------
__device__ __forceinline__ unsigned compute_ou(unsigned i, float v, float dp, float g) {
  if (v == 0.0f) return 0u;
  unsigned bits = tf_bits(i);
  float u = uniform_from_bits(bits);
  float lg = xla_logf(u);
  float gum = -xla_logf(-lg);
  float t = __fsub_rn(1.0f, v);
  float lx = __fsub_rn(__fmul_rn(dp, t), __fmul_rn(g, v));
  float ex = xla_expf(-fabsf(lx));
  float l1p = xla_log1pf(ex);
  float lp = -(__fadd_rn(fmaxf(-lx, 0.0f), l1p));
  float key = __fadd_rn(lp, gum);
  return encode_f(key);
}

// ---------------- APPROX key (HW transcendentals, |err| <= ~1e-5) ----------
__device__ __forceinline__ float approx_key(unsigned i, float v, float dp, float g) {
  if (v == 0.0f) return -INFINITY;
  unsigned bits = tf_bits(i);
  float u = uniform_from_bits(bits);
  float lg = __logf(u);
  float gum = -__logf(-lg);
  float t = __fsub_rn(1.0f, v);
  float lx = __fsub_rn(__fmul_rn(dp, t), __fmul_rn(g, v));
  float ex = __expf(-fabsf(lx));
  float for_small = __fmul_rn(__fadd_rn(__fmul_rn(-0.5f, ex), 1.0f), ex);
  float l1p = (fabsf(ex) < 1e-4f) ? for_small : __logf(__fadd_rn(ex, 1.0f));
  float lp = -(__fadd_rn(fmaxf(-lx, 0.0f), l1p));
  return __fadd_rn(lp, gum);
}

// ---------------- band setter (device, shared by sample/verify phases) -----
// state: [2]=blo_code [3]=bhi_code [12]=sh
//        f[16..19]=blo_v,bhi_v,clo_v,chi_v   (key-space thresholds)
//        f[23..26]=C2_blo,C2_bhi,C2_clo,C2_chi   (q2-space: e^{-t}*log2e)
//        [22]=1 -> q2-space constants invalid, use key-space fallback
__device__ __forceinline__ void set_band(unsigned* state, int B, int w) {
  int plo = B - w; if (plo < 32) plo = 32;      // stay clear of -NaN/-inf codes
  int phi = B + w;
  unsigned blo_c = (unsigned)plo << NBINS_SHIFT;
  float blo_v = decode_f(blo_c);
  float bhi_v; unsigned bhi_c;
  if (phi >= NBINS - 1) { bhi_v = INFINITY; bhi_c = encode_f(INFINITY); }
  else { bhi_c = (unsigned)(phi + 1) << NBINS_SHIFT; bhi_v = decode_f(bhi_c); }
  float clo_v = blo_v + MARGIN;
  float chi_v = bhi_v - MARGIN;                  // inf stays inf
  state[2] = blo_c; state[3] = bhi_c;
  state[16] = __float_as_uint(blo_v);
  state[17] = __float_as_uint(bhi_v);
  state[18] = __float_as_uint(clo_v);
  state[19] = __float_as_uint(chi_v);
  float Cb = __expf(-blo_v) * LOG2E;             // q2-space thresholds
  float Cl = __expf(-clo_v) * LOG2E;
  float Ch = (chi_v == INFINITY) ? 0.0f : __expf(-chi_v) * LOG2E;
  float Cd = (bhi_v == INFINITY) ? 0.0f : __expf(-bhi_v) * LOG2E;
  state[23] = __float_as_uint(Cb);
  state[24] = __float_as_uint(Cd);
  state[25] = __float_as_uint(Cl);
  state[26] = __float_as_uint(Ch);
  state[22] = (isfinite(Cb) && isfinite(Cl)) ? 0u : 1u;
  unsigned span = bhi_c - blo_c;
  unsigned sh = 0;
  while ((span >> sh) >= 4096u) ++sh;
  state[12] = sh;
}

// ============================================================================
// K1: sample hist (64 x 1024, 1 float4/thread) + LASTBLOCK find_sample.
// done-counter: state[30]; hist_s read back via aload. (Proven in R13.)
// ============================================================================
__global__ __launch_bounds__(1024) void sample_hist_kernel(
    const float* __restrict__ v, const float* __restrict__ dpp,
    const float* __restrict__ gp, unsigned* __restrict__ hist_s,
    unsigned* __restrict__ state, const int* __restrict__ pct_p,
    long long Etot, int nvec, int chunk, int spb, long long SN) {
  __shared__ unsigned h[NBINS];
  __shared__ unsigned s[1024];
  __shared__ int bs_sh;
  __shared__ unsigned rank_s;
  int t = threadIdx.x;
  for (int j = t; j < NBINS; j += 1024) h[j] = 0;
  __syncthreads();
  float dp = dpp[0], g = gp[0];
  if (t < spb) {
    int iv = blockIdx.x * chunk + t;
    if (iv < nvec) {
      float4 vv = reinterpret_cast<const float4*>(v)[iv];
      unsigned base = (unsigned)iv << 2;
      atomicAdd(&h[encode_f(approx_key(base + 0u, vv.x, dp, g)) >> NBINS_SHIFT], 1u);
      atomicAdd(&h[encode_f(approx_key(base + 1u, vv.y, dp, g)) >> NBINS_SHIFT], 1u);
      atomicAdd(&h[encode_f(approx_key(base + 2u, vv.z, dp, g)) >> NBINS_SHIFT], 1u);
      atomicAdd(&h[encode_f(approx_key(base + 3u, vv.w, dp, g)) >> NBINS_SHIFT], 1u);
    }
  }
  __syncthreads();
  for (int j = t; j < NBINS; j += 1024)
    if (h[j]) atomicAdd(&hist_s[j], h[j]);
  // ---- last block runs find_sample ----
  __threadfence();
  __syncthreads();
  if (t == 0) rank_s = atomicAdd(&state[30], 1u);
  __syncthreads();
  if (rank_s != (unsigned)(gridDim.x - 1)) return;
  __threadfence();
  if (t == 0) bs_sh = NBINS / 2;
  unsigned hh[8];
  unsigned tot = 0;
  #pragma unroll
  for (int j = 0; j < 8; ++j) { hh[j] = aload(&hist_s[t * 8 + j]); tot += hh[j]; }
  s[t] = tot;
  __syncthreads();
  for (int off = 1; off < 1024; off <<= 1) {
    unsigned add = (t + off < 1024) ? s[t + off] : 0u;
    __syncthreads();
    s[t] += add;
    __syncthreads();
  }
  long long k = (Etot * (long long)pct_p[0]) / 100;
  long long ks = (Etot > 0) ? (k * SN) / Etot : 0;
  if (ks < 1) ks = 1;
  long long above_next = (t < 1023) ? (long long)s[t + 1] : 0;
  if (above_next < ks && ks <= above_next + (long long)tot) {
    long long above = above_next;
    for (int b = 7; b >= 0; --b) {
      if (above < ks && ks <= above + (long long)hh[b]) { bs_sh = t * 8 + b; break; }
      above += (long long)hh[b];
    }
  }
  __syncthreads();
  if (t == 0) {
    state[6] = (unsigned)k;
    state[0] = (unsigned)bs_sh;
    if (k == 0) {
      state[15] = 0u; state[22] = 0u;
      state[2] = 0xFFFFFFFFu; state[3] = 0xFFFFFFFFu; state[12] = 0u;
      state[16] = state[17] = state[18] = state[19] = __float_as_uint(INFINITY);
      state[23] = state[24] = state[25] = state[26] = 0u;   // C=0: nothing hits
    } else {
      set_band(state, bs_sh, SLACK);
    }
  }
}

// ============================================================================
// S2: full stream pass — R14 verbatim (NO fence/ticket; proven 68us).
// q2 = fma(w2, e2, w2); drop iff q2 < Cd; band iff q2 <= Cb; sentinels
// q2 <= Ch / q2 <= Cl. mode 1 = retry clone (no-op unless state[15]==1).
// ============================================================================
__global__ __launch_bounds__(STREAM_T) void stream_kernel(
    const float* __restrict__ v, const float* __restrict__ dpp,
    const float* __restrict__ gp, float* __restrict__ out,
    unsigned* __restrict__ state, uint2* __restrict__ list, int E, int mode) {
  if (mode == 1 && state[15] == 0u) return;
  __shared__ uint2 lbuf[LBUF_CAP];
  __shared__ unsigned lcnt, lbase, s_a, s_hi, s_lo;
  if (threadIdx.x == 0) { lcnt = 0; s_a = 0; s_hi = 0; s_lo = 0; }
  __syncthreads();
  float dp = dpp[0], g = gp[0];
  int nvec = E >> 2;
  int stride = gridDim.x * STREAM_T;
  unsigned a_c = 0, hi_c = 0, lo_c = 0;

  if (state[22] == 0u) {                     // ---- fast q2-space path ----
    float Cb = __uint_as_float(state[23]);   // e^{-blo}*log2e
    float Cd = __uint_as_float(state[24]);   // e^{-bhi}*log2e
    float Cl = __uint_as_float(state[25]);   // e^{-clo}*log2e
    float Ch = __uint_as_float(state[26]);   // e^{-chi}*log2e
    float A2 = __fmul_rn(__fadd_rn(dp, g), LOG2E);
    float dp2 = __fmul_rn(dp, LOG2E);
    for (int iv = blockIdx.x * STREAM_T + threadIdx.x; iv < nvec; iv += stride) {
      float4 vv = reinterpret_cast<const float4*>(v)[iv];
      unsigned base = (unsigned)iv << 2;
      float vals[4] = {vv.x, vv.y, vv.z, vv.w};
      float q[4];
      #pragma unroll
      for (int j = 0; j < 4; ++j) {
        unsigned bits = tf_bits(base + (unsigned)j);
        float u = uniform_from_bits(bits);
        float w2 = -__builtin_amdgcn_logf(u);                        // -log2(u)
        float e2 = __builtin_amdgcn_exp2f(__fmaf_rn(A2, vals[j], -dp2)); // e^{-lx}
        float qq = __fmaf_rn(w2, e2, w2);    // q/ln2
        q[j] = (vals[j] == 0.0f) ? INFINITY : qq;
      }
      float res[4];
      #pragma unroll
      for (int j = 0; j < 4; ++j) {
        bool drop = q[j] < Cd;               // key > bhi
        a_c  += drop ? 1u : 0u;
        hi_c += (q[j] <= Ch) ? 1u : 0u;
        lo_c += (q[j] <= Cl) ? 1u : 0u;
        res[j] = drop ? 0.0f : vals[j];
        if (!drop && q[j] <= Cb) {           // key >= blo
          unsigned p = atomicAdd(&lcnt, 1u);
          uint2 ent = make_uint2(base + (unsigned)j, __float_as_uint(vals[j]));
          if (p < LBUF_CAP) lbuf[p] = ent;
          else {
            unsigned qg = atomicAdd(&state[4], 1u);
            if (qg < LIST_CAP) list[qg] = ent;
          }
        }
      }
      float4 oo; oo.x = res[0]; oo.y = res[1]; oo.z = res[2]; oo.w = res[3];
      reinterpret_cast<float4*>(out)[iv] = oo;
    }
  } else {                                   // ---- key-space fallback ----
    float blo_v = __uint_as_float(state[16]);
    float bhi_v = __uint_as_float(state[17]);
    float clo_v = __uint_as_float(state[18]);
    float chi_v = __uint_as_float(state[19]);
    for (int iv = blockIdx.x * STREAM_T + threadIdx.x; iv < nvec; iv += stride) {
      float4 vv = reinterpret_cast<const float4*>(v)[iv];
      unsigned base = (unsigned)iv << 2;
      float vals[4] = {vv.x, vv.y, vv.z, vv.w};
      float kk[4];
      #pragma unroll
      for (int j = 0; j < 4; ++j) kk[j] = approx_key(base + (unsigned)j, vals[j], dp, g);
      float res[4];
      #pragma unroll
      for (int j = 0; j < 4; ++j) {
        bool drop = kk[j] > bhi_v;
        a_c  += drop ? 1u : 0u;
        hi_c += (kk[j] >= chi_v) ? 1u : 0u;
        lo_c += (kk[j] >= clo_v) ? 1u : 0u;
        res[j] = drop ? 0.0f : vals[j];
        if (!drop && kk[j] >= blo_v) {
          unsigned p = atomicAdd(&lcnt, 1u);
          uint2 ent = make_uint2(base + (unsigned)j, __float_as_uint(vals[j]));
          if (p < LBUF_CAP) lbuf[p] = ent;
          else {
            unsigned qg = atomicAdd(&state[4], 1u);
            if (qg < LIST_CAP) list[qg] = ent;
          }
        }
      }
      float4 oo; oo.x = res[0]; oo.y = res[1]; oo.z = res[2]; oo.w = res[3];
      reinterpret_cast<float4*>(out)[iv] = oo;
    }
  }
  if (blockIdx.x == 0) {                     // tail (E % 4), key-space
    float blo_v = __uint_as_float(state[16]);
    float bhi_v = __uint_as_float(state[17]);
    float clo_v = __uint_as_float(state[18]);
    float chi_v = __uint_as_float(state[19]);
    for (int i = (nvec << 2) + threadIdx.x; i < E; i += STREAM_T) {
      float val = v[i];
      float key = approx_key((unsigned)i, val, dp, g);
      bool drop = key > bhi_v;
      a_c  += drop ? 1u : 0u;
      hi_c += (key >= chi_v) ? 1u : 0u;
      lo_c += (key >= clo_v) ? 1u : 0u;
      out[i] = drop ? 0.0f : val;
      if (!drop && key >= blo_v) {
        unsigned p = atomicAdd(&lcnt, 1u);
        uint2 ent = make_uint2((unsigned)i, __float_as_uint(val));
        if (p < LBUF_CAP) lbuf[p] = ent;
        else {
          unsigned qg = atomicAdd(&state[4], 1u);
          if (qg < LIST_CAP) list[qg] = ent;
        }
      }
    }
  }
  #pragma unroll
  for (int off = 32; off > 0; off >>= 1) {
    a_c  += __shfl_xor(a_c, off);
    hi_c += __shfl_xor(hi_c, off);
    lo_c += __shfl_xor(lo_c, off);
  }
  if ((threadIdx.x & 63) == 0) {
    if (a_c)  atomicAdd(&s_a, a_c);
    if (hi_c) atomicAdd(&s_hi, hi_c);
    if (lo_c) atomicAdd(&s_lo, lo_c);
  }
  __syncthreads();
  if (threadIdx.x == 0) {
    lbase = atomicAdd(&state[4], min(lcnt, (unsigned)LBUF_CAP));
    if (s_a)  atomicAdd(&state[5], s_a);
    if (s_hi) atomicAdd(&state[20], s_hi);
    if (s_lo) atomicAdd(&state[21], s_lo);
  }
  __syncthreads();
  unsigned n = min(lcnt, (unsigned)LBUF_CAP);
  for (unsigned j = threadIdx.x; j < n; j += STREAM_T) {
    unsigned q = lbase + j;
    if (q < LIST_CAP) list[q] = lbuf[j];
  }
}

// ============================================================================
// F2: verify sentinel counts; on failure recenter band + reset counters.
// (Separate tiny kernel — R14 proven.)
// ============================================================================
__global__ __launch_bounds__(64) void find_verify_kernel(
    unsigned* __restrict__ state) {
  if (threadIdx.x != 0) return;
  unsigned k = state[6];
  if (k == 0u) { state[15] = 0u; return; }
  unsigned hi = state[20], lo = state[21], M = state[4];
  bool cond_hi = hi < k;
  bool cond_lo = lo >= k;
  bool cond_M = M <= LIST_CAP;
  if (cond_hi && cond_lo && cond_M) { state[15] = 0u; return; }
  state[15] = 1u;
  int B = (int)state[0];
  int w = SLACK;
  if (!cond_hi)      B += 2 * SLACK - 1;   // threshold above band: move up
  else if (!cond_lo) B -= 2 * SLACK - 1;   // threshold below band: move down
  else               w = 1;                // list overflow: shrink band
  state[0] = (unsigned)B;
  set_band(state, B, w);
  state[4] = 0u; state[5] = 0u; state[20] = 0u; state[21] = 0u;
}

// ---------------- offset-code bin (clamped) --------------------------------
__device__ __forceinline__ unsigned band_bin(unsigned ec, unsigned blo,
                                             unsigned span, unsigned sh) {
  if (ec <= blo) return 0u;
  unsigned d = ec - blo;
  if (d > span) d = span;
  return d >> sh;                       // < 4096 by construction of sh
}

// ============================================================================
// K3: exact Cephes eval over band list -> elist; LDS 4096-bin hist -> global
// atomic flush into pre-zeroed hist2; LASTBLOCK find_band (state[32], aloads).
// (Proven in R13.)
// ============================================================================
__global__ __launch_bounds__(256) void exact_eval_kernel(
    const float* __restrict__ dpp, const float* __restrict__ gp,
    const uint2* __restrict__ list, unsigned* __restrict__ elist,
    unsigned* __restrict__ state, unsigned* __restrict__ hist2) {
  __shared__ unsigned h[4096];
  __shared__ unsigned sb[256];
  __shared__ unsigned rank_s;
  int t = threadIdx.x;
  for (int j = t; j < 4096; j += 256) h[j] = 0;
  __syncthreads();
  unsigned M = min(state[4], LIST_CAP);
  unsigned blo = state[2], span = state[3] - state[2], sh = state[12];
  float dp = dpp[0], g = gp[0];
  for (unsigned e = blockIdx.x * 256 + t; e < M; e += gridDim.x * 256) {
    uint2 le = list[e];
    unsigned ec = compute_ou(le.x, __uint_as_float(le.y), dp, g);
    elist[e] = ec;
    atomicAdd(&h[band_bin(ec, blo, span, sh)], 1u);
  }
  __syncthreads();
  for (int j = t; j < 4096; j += 256)
    if (h[j]) atomicAdd(&hist2[j], h[j]);
  // ---- last block runs find_band (256-thread suffix select) ----
  __threadfence();
  __syncthreads();
  if (t == 0) rank_s = atomicAdd(&state[32], 1u);
  __syncthreads();
  if (rank_s != (unsigned)(gridDim.x - 1)) return;
  __threadfence();
  unsigned hh[16];
  unsigned tot = 0;
  #pragma unroll
  for (int j = 0; j < 16; ++j) { hh[j] = aload(&hist2[t * 16 + j]); tot += hh[j]; }
  sb[t] = tot;
  __syncthreads();
  for (int off = 1; off < 256; off <<= 1) {
    unsigned add = (t + off < 256) ? sb[t + off] : 0u;
    __syncthreads();
    sb[t] += add;
    __syncthreads();
  }
  unsigned kp = aload(&state[6]) - aload(&state[5]);   // k - |A|
  if (kp == 0u || kp > sb[0]) {
    if (t == 0) { state[7] = 0xFFFFFFFFu; state[8] = 0u; }
    return;
  }
  unsigned above_next = (t < 255) ? sb[t + 1] : 0u;
  if (above_next < kp && kp <= sb[t]) {
    unsigned above = above_next;
    for (int b = 15; b >= 0; --b) {
      if (above < kp && kp <= above + hh[b]) {
        state[7] = (unsigned)(t * 16 + b);
        state[8] = kp - above;
        break;
      }
      above += hh[b];
    }
  }
}

// ============================================================================
// K4: drop band members with bin > Eb; bin == Eb -> mini; LASTBLOCK ties
// (all-pairs rank by (ec desc, idx asc); mini via aloads; state[33] ticket).
// (Proven in R13.)
// ============================================================================
__global__ __launch_bounds__(256) void band_drop_kernel(
    const uint2* __restrict__ list, const unsigned* __restrict__ elist,
    unsigned* __restrict__ state, float* __restrict__ out,
    uint2* __restrict__ mini) {
  __shared__ uint2 tile[TIES_TILE];
  __shared__ unsigned rank_s;
  int t = threadIdx.x;
  unsigned M = min(state[4], LIST_CAP);
  unsigned Eb = state[7];
  unsigned blo = state[2], span = state[3] - state[2], sh = state[12];
  for (unsigned e = blockIdx.x * 256 + t; e < M; e += gridDim.x * 256) {
    unsigned ec = elist[e];
    unsigned bin = band_bin(ec, blo, span, sh);
    if (bin > Eb) out[list[e].x] = 0.0f;
    else if (bin == Eb) {
      unsigned q = atomicAdd(&state[11], 1u);
      if (q < MINI_CAP) mini[q] = make_uint2(ec, list[e].x);
    }
  }
  // ---- last block runs ties ----
  __threadfence();
  __syncthreads();
  if (t == 0) rank_s = atomicAdd(&state[33], 1u);
  __syncthreads();
  if (rank_s != (unsigned)(gridDim.x - 1)) return;
  __threadfence();
  unsigned m = min(aload(&state[11]), MINI_CAP);
  unsigned r = state[8];
  if (r == 0u || m == 0u) return;
  for (unsigned e0 = 0; e0 < m; e0 += 256) {
    unsigned e = e0 + t;
    bool valid = e < m;
    unsigned my_ec = 0, my_idx = 0;
    if (valid) {
      const unsigned* mp = (const unsigned*)&mini[e];
      my_ec = aload(mp); my_idx = aload(mp + 1);
    }
    unsigned rank = 0;
    for (unsigned t0 = 0; t0 < m; t0 += TIES_TILE) {
      unsigned tn = min((unsigned)TIES_TILE, m - t0);
      __syncthreads();
      for (unsigned j = t; j < tn; j += 256) {
        const unsigned* mp = (const unsigned*)&mini[t0 + j];
        tile[j] = make_uint2(aload(mp), aload(mp + 1));
      }
      __syncthreads();
      if (valid) {
        for (unsigned j = 0; j < tn; ++j) {
          uint2 o = tile[j];
          rank += (o.x > my_ec || (o.x == my_ec && o.y < my_idx)) ? 1u : 0u;
        }
      }
    }
    if (valid && rank < r) out[my_idx] = 0.0f;
  }
}

// ---------------- launch ----------------------------------------------------
extern "C" void kernel_launch(void* const* d_in, const int* in_sizes, int n_in,
                              void* d_out, int out_size, void* d_ws, size_t ws_size,
                              hipStream_t stream) {
  const float* v  = (const float*)d_in[0];
  const float* dp = (const float*)d_in[1];
  const float* g  = (const float*)d_in[2];
  const int* pct  = (const int*)d_in[3];
  float* out = (float*)d_out;
  int E = in_sizes[0];

  uint8_t* ws = (uint8_t*)d_ws;
  // Layout (25 MiB total):
  //   state  @0      (1 KiB)   } memset [0, 52 KiB) zeroes these each call
  //   hist_s @4KiB   (32 KiB)  }
  //   hist2  @36KiB  (16 KiB)  }
  //   mini   @64KiB  (128 KiB)   (count-guarded)
  //   list   @1MiB   (16 MiB)    (count-guarded)
  //   elist  @17MiB  (8 MiB)     (count-guarded)
  const size_t STATE_OFF = 0;
  const size_t HISTS_OFF = 4 * 1024;
  const size_t HIST2_OFF = 36 * 1024;
  const size_t MINI_OFF  = 64 * 1024;
  const size_t LIST_OFF  = (size_t)1 << 20;
  const size_t ELIST_OFF = (size_t)17 << 20;
  const size_t NEED = ELIST_OFF + (size_t)LIST_CAP * 4;   // 25 MiB

  if (ws_size < NEED) {
    // cannot run selection; fail loudly via passthrough
    (void)hipMemcpyAsync(out, v, (size_t)E * 4, hipMemcpyDeviceToDevice, stream);
    return;
  }

  unsigned* state  = (unsigned*)(ws + STATE_OFF);
  unsigned* hist_s = (unsigned*)(ws + HISTS_OFF);
  unsigned* hist2  = (unsigned*)(ws + HIST2_OFF);
  uint2*    mini   = (uint2*)(ws + MINI_OFF);
  uint2*    list   = (uint2*)(ws + LIST_OFF);
  unsigned* elist  = (unsigned*)(ws + ELIST_OFF);

  int nvec = E >> 2;
  int chunk = (nvec + NBS - 1) / NBS;
  int spb = chunk < 1024 ? chunk : 1024;
  long long SN = (long long)NBS * (long long)spb * 4;

  (void)hipMemsetAsync(ws, 0, 52 * 1024, stream);   // state + hist_s + hist2

  sample_hist_kernel<<<NBS, 1024, 0, stream>>>(v, dp, g, hist_s, state, pct,
                                               (long long)E, nvec, chunk, spb, SN);
  stream_kernel<<<NBSTREAM, STREAM_T, 0, stream>>>(v, dp, g, out, state, list, E, 0);
  find_verify_kernel<<<1, 64, 0, stream>>>(state);
  stream_kernel<<<NBSTREAM, STREAM_T, 0, stream>>>(v, dp, g, out, state, list, E, 1);
  exact_eval_kernel<<<NB2, 256, 0, stream>>>(dp, g, list, elist, state, hist2);
  band_drop_kernel<<<NB3, 256, 0, stream>>>(list, elist, state, out, mini);
}

// Round 16
// 124.706 us; speedup vs baseline: 1.1846x; 1.1846x over previous
//
#include <hip/hip_runtime.h>
#include <hip/hip_bf16.h>
#include <stdint.h>

// ============================================================================
// AdaptiveEdgeDropping: out = matrix with top-k (k = E*pct/100) of
// (log_sigmoid(dp*(1-v) - g*v) + gumbel(key=42)) zeroed.  BIT-EXACT.
//
// Round 16: exact revert to R14 — the best measured configuration (124.8us).
// R15's fused tail (+23us), R13's fused stream (+220us), R12's plain-load
// fusion (incorrect) all lose on this 8-XCD part: separate dispatches are the
// cheapest cross-block barrier. Structure:
//  - sample (1.5%) -> provisional band; sentinel-verified vs exact rank-k.
//  - ONE full stream pass, q2-space base-2 math:
//      key >= t  <=>  q2 <= e^{-t}*log2e,
//      q2 = fma(w2, e2, w2), w2 = -v_log_f32(u), e2 = v_exp_f32(A2*v - dp2).
//  - conditional retry clone (no-op when verification passes).
//  - exact Cephes eval on the ~150K-member band; atomic-free radix select;
//    stable tie rank (lowest index first). All bit-exact vs JAX-CPU.
// ============================================================================

#define NBINS 8192
#define NBINS_SHIFT 19            // approx code >> 19 -> 13-bit bin
#define NBS 256                   // sample blocks
#define NBSTREAM 1024             // stream blocks  (R8-proven shape)
#define STREAM_T 512              // stream threads/block
#define NB2 512                   // exact_eval blocks
#define LIST_CAP 2097152u
#define MINI_CAP 16384u
#define LBUF_CAP 2048
#define TIES_TILE 4096
#define SLACK 2
#define MARGIN 2.0e-4f
#define LOG2E 1.44269504088896340736f

// ---------------- threefry2x32, key=(0,42), counts=(0,i), out = x0^x1 -------
__device__ __forceinline__ unsigned tf_bits(unsigned i) {
  const unsigned ks0 = 0u;
  const unsigned ks1 = 42u;
  const unsigned ks2 = 0x1BD11BDAu ^ 0u ^ 42u;
  unsigned x0 = 0u + ks0;
  unsigned x1 = i + ks1;
#define TF_R(rot) { x0 += x1; \
  x1 = __builtin_amdgcn_alignbit(x1, x1, 32u - (rot)); x1 ^= x0; }
  TF_R(13) TF_R(15) TF_R(26) TF_R(6)
  x0 += ks1; x1 += ks2 + 1u;
  TF_R(17) TF_R(29) TF_R(16) TF_R(24)
  x0 += ks2; x1 += ks0 + 2u;
  TF_R(13) TF_R(15) TF_R(26) TF_R(6)
  x0 += ks0; x1 += ks1 + 3u;
  TF_R(17) TF_R(29) TF_R(16) TF_R(24)
  x0 += ks1; x1 += ks2 + 4u;
  TF_R(13) TF_R(15) TF_R(26) TF_R(6)
  x0 += ks2; x1 += ks0 + 5u;
#undef TF_R
  return x0 ^ x1;
}

// ---------------- jax.random.uniform(minval=1e-7, maxval=1-1e-7) -----------
__device__ __forceinline__ float uniform_from_bits(unsigned bits) {
  unsigned fb = (bits >> 9) | 0x3f800000u;
  float f = __uint_as_float(fb) - 1.0f;
  const float minv = 1e-7f;
  const float maxv = __uint_as_float(0x3F7FFFFEu);   // f32(1.0 - 1e-7)
  float r = __fsub_rn(maxv, minv);
  float u = __fadd_rn(__fmul_rn(f, r), minv);
  return fmaxf(minv, u);
}

// ---------------- XLA-CPU Cephes expf (unfused) ----------------------------
__device__ __forceinline__ float xla_expf(float input) {
  const float exp_hi = 88.3762626647950f;
  const float exp_lo = -88.3762626647949f;
  float x = fminf(fmaxf(input, exp_lo), exp_hi);
  float fx = floorf(__fadd_rn(__fmul_rn(x, 1.44269504088896341f), 0.5f));
  float tmp = __fmul_rn(0.693359375f, fx);
  float z = __fmul_rn(-2.12194440e-4f, fx);
  x = __fsub_rn(x, tmp);
  x = __fsub_rn(x, z);
  z = __fmul_rn(x, x);
  float y = __fadd_rn(__fmul_rn(x, 1.9875691500e-4f), 1.3981999507e-3f);
  y = __fadd_rn(__fmul_rn(y, x), 8.3334519073e-3f);
  y = __fadd_rn(__fmul_rn(y, x), 4.1665795894e-2f);
  y = __fadd_rn(__fmul_rn(y, x), 1.6666665459e-1f);
  y = __fadd_rn(__fmul_rn(y, x), 5.0000001201e-1f);
  y = __fadd_rn(__fmul_rn(y, z), x);
  y = __fadd_rn(1.0f, y);
  int n = (int)fx;
  float p2n = __int_as_float((n + 0x7f) << 23);
  return fmaxf(__fmul_rn(y, p2n), input);
}

// ---------------- XLA-CPU Cephes logf (Estrin, unfused) --------------------
__device__ __forceinline__ float xla_logf(float input) {
  float t0 = fmaxf(input, __uint_as_float(0x00800000u));
  unsigned ib = __float_as_uint(t0);
  int emm0 = (int)(ib >> 23) - 0x7f;
  float e = __fadd_rn(1.0f, (float)emm0);
  float m = __uint_as_float((ib & 0x807fffffu) | 0x3f000000u);
  bool mask = m < 0.707106781186547524f;
  float t1 = mask ? m : 0.0f;
  m = __fsub_rn(m, 1.0f);
  e = __fsub_rn(e, mask ? 1.0f : 0.0f);
  m = __fadd_rn(m, t1);
  float x2 = __fmul_rn(m, m);
  float x3 = __fmul_rn(x2, m);
  float y  = __fadd_rn(__fmul_rn(m, 7.0376836292e-2f), -1.1514610310e-1f);
  float y1 = __fadd_rn(__fmul_rn(m, -1.2420140846e-1f), 1.4249322787e-1f);
  float y2 = __fadd_rn(__fmul_rn(m, 2.0000714765e-1f), -2.4999993993e-1f);
  y  = __fadd_rn(__fmul_rn(y, m), 1.1676998740e-1f);
  y1 = __fadd_rn(__fmul_rn(y1, m), -1.6668057665e-1f);
  y2 = __fadd_rn(__fmul_rn(y2, m), 3.3333331174e-1f);
  y = __fadd_rn(__fmul_rn(y, x3), y1);
  y = __fadd_rn(__fmul_rn(y, x3), y2);
  y = __fmul_rn(y, x3);
  y = __fadd_rn(y, __fmul_rn(-2.12194440e-4f, e));
  y = __fsub_rn(y, __fmul_rn(0.5f, x2));
  m = __fadd_rn(m, y);
  m = __fadd_rn(m, __fmul_rn(0.693359375f, e));
  return m;
}

// ---------------- XLA elemental log1p --------------------------------------
__device__ __forceinline__ float xla_log1pf(float x) {
  float for_large = xla_logf(__fadd_rn(x, 1.0f));
  float for_small = __fmul_rn(__fadd_rn(__fmul_rn(-0.5f, x), 1.0f), x);
  return (fabsf(x) < 1e-4f) ? for_small : for_large;
}

// ---------------- monotone code <-> float ----------------------------------
__device__ __forceinline__ unsigned encode_f(float f) {
  unsigned b = __float_as_uint(f);
  return (b & 0x80000000u) ? ~b : (b | 0x80000000u);
}
__device__ __forceinline__ float decode_f(unsigned c) {
  unsigned b = (c & 0x80000000u) ? (c ^ 0x80000000u) : ~c;
  return __uint_as_float(b);
}

// ---------------- EXACT per-element key code (verified bit-exact) ----------
__device__ __forceinline__ unsigned compute_ou(unsigned i, float v, float dp, float g) {
  if (v == 0.0f) return 0u;
  unsigned bits = tf_bits(i);
  float u = uniform_from_bits(bits);
  float lg = xla_logf(u);
  float gum = -xla_logf(-lg);
  float t = __fsub_rn(1.0f, v);
  float lx = __fsub_rn(__fmul_rn(dp, t), __fmul_rn(g, v));
  float ex = xla_expf(-fabsf(lx));
  float l1p = xla_log1pf(ex);
  float lp = -(__fadd_rn(fmaxf(-lx, 0.0f), l1p));
  float key = __fadd_rn(lp, gum);
  return encode_f(key);
}

// ---------------- APPROX key (HW transcendentals, |err| <= ~1e-5) ----------
__device__ __forceinline__ float approx_key(unsigned i, float v, float dp, float g) {
  if (v == 0.0f) return -INFINITY;
  unsigned bits = tf_bits(i);
  float u = uniform_from_bits(bits);
  float lg = __logf(u);
  float gum = -__logf(-lg);
  float t = __fsub_rn(1.0f, v);
  float lx = __fsub_rn(__fmul_rn(dp, t), __fmul_rn(g, v));
  float ex = __expf(-fabsf(lx));
  float for_small = __fmul_rn(__fadd_rn(__fmul_rn(-0.5f, ex), 1.0f), ex);
  float l1p = (fabsf(ex) < 1e-4f) ? for_small : __logf(__fadd_rn(ex, 1.0f));
  float lp = -(__fadd_rn(fmaxf(-lx, 0.0f), l1p));
  return __fadd_rn(lp, gum);
}

// ---------------- band setter (shared by F1/F2) -----------------------------
// state: [2]=blo_code [3]=bhi_code [12]=sh
//        f[16..19]=blo_v,bhi_v,clo_v,chi_v   (key-space thresholds)
//        f[23..26]=C2_blo,C2_bhi,C2_clo,C2_chi   (q2-space: e^{-t}*log2e)
//        [22]=1 -> q2-space constants invalid, use key-space fallback
__device__ __forceinline__ void set_band(unsigned* state, int B, int w) {
  int plo = B - w; if (plo < 32) plo = 32;      // stay clear of -NaN/-inf codes
  int phi = B + w;
  unsigned blo_c = (unsigned)plo << NBINS_SHIFT;
  float blo_v = decode_f(blo_c);
  float bhi_v; unsigned bhi_c;
  if (phi >= NBINS - 1) { bhi_v = INFINITY; bhi_c = encode_f(INFINITY); }
  else { bhi_c = (unsigned)(phi + 1) << NBINS_SHIFT; bhi_v = decode_f(bhi_c); }
  float clo_v = blo_v + MARGIN;
  float chi_v = bhi_v - MARGIN;                  // inf stays inf
  state[2] = blo_c; state[3] = bhi_c;
  state[16] = __float_as_uint(blo_v);
  state[17] = __float_as_uint(bhi_v);
  state[18] = __float_as_uint(clo_v);
  state[19] = __float_as_uint(chi_v);
  float Cb = __expf(-blo_v) * LOG2E;             // q2-space thresholds
  float Cl = __expf(-clo_v) * LOG2E;
  float Ch = (chi_v == INFINITY) ? 0.0f : __expf(-chi_v) * LOG2E;
  float Cd = (bhi_v == INFINITY) ? 0.0f : __expf(-bhi_v) * LOG2E;
  state[23] = __float_as_uint(Cb);
  state[24] = __float_as_uint(Cd);
  state[25] = __float_as_uint(Cl);
  state[26] = __float_as_uint(Ch);
  state[22] = (isfinite(Cb) && isfinite(Cl)) ? 0u : 1u;
  unsigned span = bhi_c - blo_c;
  unsigned sh = 0;
  while ((span >> sh) >= 4096u) ++sh;
  state[12] = sh;
}

// ============================================================================
// S1: sample hist — NBS blocks x 256 threads, 1 float4 each; LDS hist; flush.
// ============================================================================
__global__ __launch_bounds__(256) void sample_hist_kernel(
    const float* __restrict__ v, const float* __restrict__ dpp,
    const float* __restrict__ gp, unsigned* __restrict__ hist_s,
    int nvec, int chunk, int spb) {
  __shared__ unsigned h[NBINS];
  for (int j = threadIdx.x; j < NBINS; j += 256) h[j] = 0;
  __syncthreads();
  float dp = dpp[0], g = gp[0];
  int t = threadIdx.x;
  if (t < spb) {
    int iv = blockIdx.x * chunk + t;
    if (iv < nvec) {
      float4 vv = reinterpret_cast<const float4*>(v)[iv];
      unsigned base = (unsigned)iv << 2;
      atomicAdd(&h[encode_f(approx_key(base + 0u, vv.x, dp, g)) >> NBINS_SHIFT], 1u);
      atomicAdd(&h[encode_f(approx_key(base + 1u, vv.y, dp, g)) >> NBINS_SHIFT], 1u);
      atomicAdd(&h[encode_f(approx_key(base + 2u, vv.z, dp, g)) >> NBINS_SHIFT], 1u);
      atomicAdd(&h[encode_f(approx_key(base + 3u, vv.w, dp, g)) >> NBINS_SHIFT], 1u);
    }
  }
  __syncthreads();
  for (int j = threadIdx.x; j < NBINS; j += 256)
    if (h[j]) atomicAdd(&hist_s[j], h[j]);
}

// ============================================================================
// F1: sample select -> band around sample bin B. state[6]=k, state[0]=B.
// ============================================================================
__global__ __launch_bounds__(1024) void find_sample_kernel(
    const unsigned* __restrict__ hist_s, unsigned* __restrict__ state,
    const int* __restrict__ pct_p, long long Etot, long long SN) {
  __shared__ unsigned s[1024];
  __shared__ int bs_sh;
  int t = threadIdx.x;
  if (t == 0) bs_sh = NBINS / 2;
  unsigned hh[8];
  unsigned tot = 0;
  #pragma unroll
  for (int j = 0; j < 8; ++j) { hh[j] = hist_s[t * 8 + j]; tot += hh[j]; }
  s[t] = tot;
  __syncthreads();
  for (int off = 1; off < 1024; off <<= 1) {
    unsigned add = (t + off < 1024) ? s[t + off] : 0u;
    __syncthreads();
    s[t] += add;
    __syncthreads();
  }
  long long k = (Etot * (long long)pct_p[0]) / 100;
  long long ks = (Etot > 0) ? (k * SN) / Etot : 0;
  if (ks < 1) ks = 1;
  long long above_next = (t < 1023) ? (long long)s[t + 1] : 0;
  if (above_next < ks && ks <= above_next + (long long)tot) {
    long long above = above_next;
    for (int b = 7; b >= 0; --b) {
      if (above < ks && ks <= above + (long long)hh[b]) { bs_sh = t * 8 + b; break; }
      above += (long long)hh[b];
    }
  }
  __syncthreads();
  if (t == 0) {
    state[6] = (unsigned)k;
    state[0] = (unsigned)bs_sh;
    if (k == 0) {
      state[15] = 0u; state[22] = 0u;
      state[2] = 0xFFFFFFFFu; state[3] = 0xFFFFFFFFu; state[12] = 0u;
      state[16] = state[17] = state[18] = state[19] = __float_as_uint(INFINITY);
      state[23] = state[24] = state[25] = state[26] = 0u;   // C=0: nothing hits
    } else {
      set_band(state, bs_sh, SLACK);
    }
  }
}

// ============================================================================
// S2: full pass (R10 geometry). q2 = fma(w2, e2, w2); drop iff q2 < Cd;
// band iff q2 <= Cb; sentinels q2 <= Ch / q2 <= Cl. mode 1 = retry clone.
// ============================================================================
__global__ __launch_bounds__(STREAM_T) void stream_kernel(
    const float* __restrict__ v, const float* __restrict__ dpp,
    const float* __restrict__ gp, float* __restrict__ out,
    unsigned* __restrict__ state, uint2* __restrict__ list, int E, int mode) {
  if (mode == 1 && state[15] == 0u) return;
  __shared__ uint2 lbuf[LBUF_CAP];
  __shared__ unsigned lcnt, lbase, s_a, s_hi, s_lo;
  if (threadIdx.x == 0) { lcnt = 0; s_a = 0; s_hi = 0; s_lo = 0; }
  __syncthreads();
  float dp = dpp[0], g = gp[0];
  int nvec = E >> 2;
  int stride = gridDim.x * STREAM_T;
  unsigned a_c = 0, hi_c = 0, lo_c = 0;

  if (state[22] == 0u) {                     // ---- fast q2-space path ----
    float Cb = __uint_as_float(state[23]);   // e^{-blo}*log2e
    float Cd = __uint_as_float(state[24]);   // e^{-bhi}*log2e
    float Cl = __uint_as_float(state[25]);   // e^{-clo}*log2e
    float Ch = __uint_as_float(state[26]);   // e^{-chi}*log2e
    float A2 = __fmul_rn(__fadd_rn(dp, g), LOG2E);
    float dp2 = __fmul_rn(dp, LOG2E);
    for (int iv = blockIdx.x * STREAM_T + threadIdx.x; iv < nvec; iv += stride) {
      float4 vv = reinterpret_cast<const float4*>(v)[iv];
      unsigned base = (unsigned)iv << 2;
      float vals[4] = {vv.x, vv.y, vv.z, vv.w};
      float q[4];
      #pragma unroll
      for (int j = 0; j < 4; ++j) {
        unsigned bits = tf_bits(base + (unsigned)j);
        float u = uniform_from_bits(bits);
        float w2 = -__builtin_amdgcn_logf(u);                        // -log2(u)
        float e2 = __builtin_amdgcn_exp2f(__fmaf_rn(A2, vals[j], -dp2)); // e^{-lx}
        float qq = __fmaf_rn(w2, e2, w2);    // q/ln2
        q[j] = (vals[j] == 0.0f) ? INFINITY : qq;
      }
      float res[4];
      #pragma unroll
      for (int j = 0; j < 4; ++j) {
        bool drop = q[j] < Cd;               // key > bhi
        a_c  += drop ? 1u : 0u;
        hi_c += (q[j] <= Ch) ? 1u : 0u;
        lo_c += (q[j] <= Cl) ? 1u : 0u;
        res[j] = drop ? 0.0f : vals[j];
        if (!drop && q[j] <= Cb) {           // key >= blo
          unsigned p = atomicAdd(&lcnt, 1u);
          uint2 ent = make_uint2(base + (unsigned)j, __float_as_uint(vals[j]));
          if (p < LBUF_CAP) lbuf[p] = ent;
          else {
            unsigned qg = atomicAdd(&state[4], 1u);
            if (qg < LIST_CAP) list[qg] = ent;
          }
        }
      }
      float4 oo; oo.x = res[0]; oo.y = res[1]; oo.z = res[2]; oo.w = res[3];
      reinterpret_cast<float4*>(out)[iv] = oo;
    }
  } else {                                   // ---- key-space fallback ----
    float blo_v = __uint_as_float(state[16]);
    float bhi_v = __uint_as_float(state[17]);
    float clo_v = __uint_as_float(state[18]);
    float chi_v = __uint_as_float(state[19]);
    for (int iv = blockIdx.x * STREAM_T + threadIdx.x; iv < nvec; iv += stride) {
      float4 vv = reinterpret_cast<const float4*>(v)[iv];
      unsigned base = (unsigned)iv << 2;
      float vals[4] = {vv.x, vv.y, vv.z, vv.w};
      float kk[4];
      #pragma unroll
      for (int j = 0; j < 4; ++j) kk[j] = approx_key(base + (unsigned)j, vals[j], dp, g);
      float res[4];
      #pragma unroll
      for (int j = 0; j < 4; ++j) {
        bool drop = kk[j] > bhi_v;
        a_c  += drop ? 1u : 0u;
        hi_c += (kk[j] >= chi_v) ? 1u : 0u;
        lo_c += (kk[j] >= clo_v) ? 1u : 0u;
        res[j] = drop ? 0.0f : vals[j];
        if (!drop && kk[j] >= blo_v) {
          unsigned p = atomicAdd(&lcnt, 1u);
          uint2 ent = make_uint2(base + (unsigned)j, __float_as_uint(vals[j]));
          if (p < LBUF_CAP) lbuf[p] = ent;
          else {
            unsigned qg = atomicAdd(&state[4], 1u);
            if (qg < LIST_CAP) list[qg] = ent;
          }
        }
      }
      float4 oo; oo.x = res[0]; oo.y = res[1]; oo.z = res[2]; oo.w = res[3];
      reinterpret_cast<float4*>(out)[iv] = oo;
    }
  }
  if (blockIdx.x == 0) {                     // tail (E % 4), key-space
    float blo_v = __uint_as_float(state[16]);
    float bhi_v = __uint_as_float(state[17]);
    float clo_v = __uint_as_float(state[18]);
    float chi_v = __uint_as_float(state[19]);
    for (int i = (nvec << 2) + threadIdx.x; i < E; i += STREAM_T) {
      float val = v[i];
      float key = approx_key((unsigned)i, val, dp, g);
      bool drop = key > bhi_v;
      a_c  += drop ? 1u : 0u;
      hi_c += (key >= chi_v) ? 1u : 0u;
      lo_c += (key >= clo_v) ? 1u : 0u;
      out[i] = drop ? 0.0f : val;
      if (!drop && key >= blo_v) {
        unsigned p = atomicAdd(&lcnt, 1u);
        uint2 ent = make_uint2((unsigned)i, __float_as_uint(val));
        if (p < LBUF_CAP) lbuf[p] = ent;
        else {
          unsigned qg = atomicAdd(&state[4], 1u);
          if (qg < LIST_CAP) list[qg] = ent;
        }
      }
    }
  }
  #pragma unroll
  for (int off = 32; off > 0; off >>= 1) {
    a_c  += __shfl_xor(a_c, off);
    hi_c += __shfl_xor(hi_c, off);
    lo_c += __shfl_xor(lo_c, off);
  }
  if ((threadIdx.x & 63) == 0) {
    if (a_c)  atomicAdd(&s_a, a_c);
    if (hi_c) atomicAdd(&s_hi, hi_c);
    if (lo_c) atomicAdd(&s_lo, lo_c);
  }
  __syncthreads();
  if (threadIdx.x == 0) {
    lbase = atomicAdd(&state[4], min(lcnt, (unsigned)LBUF_CAP));
    if (s_a)  atomicAdd(&state[5], s_a);
    if (s_hi) atomicAdd(&state[20], s_hi);
    if (s_lo) atomicAdd(&state[21], s_lo);
  }
  __syncthreads();
  unsigned n = min(lcnt, (unsigned)LBUF_CAP);
  for (unsigned j = threadIdx.x; j < n; j += STREAM_T) {
    unsigned q = lbase + j;
    if (q < LIST_CAP) list[q] = lbuf[j];
  }
}

// ============================================================================
// F2: verify sentinel counts; on failure recenter band + reset counters.
// ============================================================================
__global__ __launch_bounds__(64) void find_verify_kernel(
    unsigned* __restrict__ state) {
  if (threadIdx.x != 0) return;
  unsigned k = state[6];
  if (k == 0u) { state[15] = 0u; return; }
  unsigned hi = state[20], lo = state[21], M = state[4];
  bool cond_hi = hi < k;
  bool cond_lo = lo >= k;
  bool cond_M = M <= LIST_CAP;
  if (cond_hi && cond_lo && cond_M) { state[15] = 0u; return; }
  state[15] = 1u;
  int B = (int)state[0];
  int w = SLACK;
  if (!cond_hi)      B += 2 * SLACK - 1;   // threshold above band: move up
  else if (!cond_lo) B -= 2 * SLACK - 1;   // threshold below band: move down
  else               w = 1;                // list overflow: shrink band
  state[0] = (unsigned)B;
  set_band(state, B, w);
  state[4] = 0u; state[5] = 0u; state[20] = 0u; state[21] = 0u;
}

// ---------------- offset-code bin (clamped) --------------------------------
__device__ __forceinline__ unsigned band_bin(unsigned ec, unsigned blo,
                                             unsigned span, unsigned sh) {
  if (ec <= blo) return 0u;
  unsigned d = ec - blo;
  if (d > span) d = span;
  return d >> sh;                       // < 4096 by construction of sh
}

// ============================================================================
// T1: dense exact eval over band list (vbits inline) -> elist; LDS 4096-bin
// hist of (ec - blo) >> sh; per-block row flush (no global atomics).
// ============================================================================
__global__ __launch_bounds__(256) void exact_eval_kernel(
    const float* __restrict__ dpp, const float* __restrict__ gp,
    const uint2* __restrict__ list, unsigned* __restrict__ elist,
    const unsigned* __restrict__ state, unsigned* __restrict__ blockhist2) {
  __shared__ unsigned h[4096];
  for (int j = threadIdx.x; j < 4096; j += 256) h[j] = 0;
  __syncthreads();
  unsigned M = min(state[4], LIST_CAP);
  unsigned blo = state[2], span = state[3] - state[2], sh = state[12];
  float dp = dpp[0], g = gp[0];
  for (unsigned e = blockIdx.x * 256 + threadIdx.x; e < M; e += gridDim.x * 256) {
    uint2 le = list[e];
    unsigned ec = compute_ou(le.x, __uint_as_float(le.y), dp, g);
    elist[e] = ec;
    atomicAdd(&h[band_bin(ec, blo, span, sh)], 1u);
  }
  __syncthreads();
  unsigned* row = blockhist2 + (size_t)blockIdx.x * 4096;
  for (int j = threadIdx.x; j < 4096; j += 256) row[j] = h[j];
}

// ============================================================================
// T2: hist2[j] = sum_b blockhist2[b][j]  (coalesced columns, no atomics)
// ============================================================================
__global__ __launch_bounds__(256) void reduce_hist2_kernel(
    const unsigned* __restrict__ blockhist2, unsigned* __restrict__ hist2) {
  int j = blockIdx.x * 256 + threadIdx.x;     // 16 blocks -> 4096 threads
  unsigned s = 0;
  for (int b = 0; b < NB2; ++b) s += blockhist2[(size_t)b * 4096 + j];
  hist2[j] = s;
}

// ============================================================================
// T3: suffix select over 4096 offset bins. kp = k - |A|. [7]=Eb, [8]=r.
// ============================================================================
__global__ __launch_bounds__(1024) void find_band_kernel(
    const unsigned* __restrict__ hist2, unsigned* __restrict__ state) {
  __shared__ unsigned s[1024];
  int t = threadIdx.x;
  unsigned hh[4];
  unsigned tot = 0;
  #pragma unroll
  for (int j = 0; j < 4; ++j) { hh[j] = hist2[t * 4 + j]; tot += hh[j]; }
  s[t] = tot;
  __syncthreads();
  for (int off = 1; off < 1024; off <<= 1) {
    unsigned add = (t + off < 1024) ? s[t + off] : 0u;
    __syncthreads();
    s[t] += add;
    __syncthreads();
  }
  unsigned kp = state[6] - state[5];          // k - |A|
  if (kp == 0u || kp > s[0]) {
    if (t == 0) { state[7] = 0xFFFFFFFFu; state[8] = 0u; }
    return;
  }
  unsigned above_next = (t < 1023) ? s[t + 1] : 0u;
  if (above_next < kp && kp <= s[t]) {
    unsigned above = above_next;
    for (int b = 3; b >= 0; --b) {
      if (above < kp && kp <= above + hh[b]) {
        state[7] = (unsigned)(t * 4 + b);
        state[8] = kp - above;
        break;
      }
      above += hh[b];
    }
  }
}

// ============================================================================
// T4: drop band members with bin > Eb; bin == Eb -> mini (ec, idx).
// ============================================================================
__global__ __launch_bounds__(256) void band_drop_kernel(
    const uint2* __restrict__ list, const unsigned* __restrict__ elist,
    unsigned* __restrict__ state, float* __restrict__ out,
    uint2* __restrict__ mini) {
  unsigned M = min(state[4], LIST_CAP);
  unsigned Eb = state[7];
  unsigned blo = state[2], span = state[3] - state[2], sh = state[12];
  for (unsigned e = blockIdx.x * 256 + threadIdx.x; e < M; e += gridDim.x * 256) {
    unsigned ec = elist[e];
    unsigned bin = band_bin(ec, blo, span, sh);
    if (bin > Eb) out[list[e].x] = 0.0f;
    else if (bin == Eb) {
      unsigned q = atomicAdd(&state[11], 1u);
      if (q < MINI_CAP) mini[q] = make_uint2(ec, list[e].x);
    }
  }
}

// ============================================================================
// T5: tiled all-pairs rank among mini by (ec desc, idx asc); drop top r.
// ============================================================================
__global__ __launch_bounds__(1024) void mini_ties_kernel(
    const uint2* __restrict__ mini, const unsigned* __restrict__ state,
    float* __restrict__ out) {
  __shared__ uint2 tile[TIES_TILE];
  unsigned m = min(state[11], MINI_CAP);
  unsigned r = state[8];
  if (r == 0u || m == 0u) return;
  int tid = threadIdx.x;
  for (unsigned e0 = 0; e0 < m; e0 += blockDim.x) {
    unsigned e = e0 + tid;
    bool valid = e < m;
    unsigned my_ec = 0, my_idx = 0;
    if (valid) { uint2 me = mini[e]; my_ec = me.x; my_idx = me.y; }
    unsigned rank = 0;
    for (unsigned t0 = 0; t0 < m; t0 += TIES_TILE) {
      unsigned tn = min((unsigned)TIES_TILE, m - t0);
      __syncthreads();
      for (unsigned j = tid; j < tn; j += blockDim.x) tile[j] = mini[t0 + j];
      __syncthreads();
      if (valid) {
        for (unsigned j = 0; j < tn; ++j) {
          uint2 o = tile[j];
          rank += (o.x > my_ec || (o.x == my_ec && o.y < my_idx)) ? 1u : 0u;
        }
      }
    }
    if (valid && rank < r) out[my_idx] = 0.0f;
  }
}

// ---------------- launch ----------------------------------------------------
extern "C" void kernel_launch(void* const* d_in, const int* in_sizes, int n_in,
                              void* d_out, int out_size, void* d_ws, size_t ws_size,
                              hipStream_t stream) {
  const float* v  = (const float*)d_in[0];
  const float* dp = (const float*)d_in[1];
  const float* g  = (const float*)d_in[2];
  const int* pct  = (const int*)d_in[3];
  float* out = (float*)d_out;
  int E = in_sizes[0];

  uint8_t* ws = (uint8_t*)d_ws;
  // Layout (33 MiB total):
  //   state  @0      (1 KiB)
  //   hist_s @4KiB   (32 KiB)        -> memset covers [0, 40KiB)
  //   hist2  @64KiB  (16 KiB)        (fully overwritten by T2)
  //   mini   @128KiB (128 KiB)       (count-guarded)
  //   bh2    @1MiB   (8 MiB)         (fully overwritten by T1)
  //   list   @9MiB   (16 MiB)        (count-guarded)
  //   elist  @25MiB  (8 MiB)         (count-guarded)
  const size_t STATE_OFF = 0;
  const size_t HISTS_OFF = 4 * 1024;
  const size_t HIST2_OFF = 64 * 1024;
  const size_t MINI_OFF  = 128 * 1024;
  const size_t BH2_OFF   = (size_t)1 << 20;
  const size_t LIST_OFF  = (size_t)9 << 20;
  const size_t ELIST_OFF = (size_t)25 << 20;
  const size_t NEED = ELIST_OFF + (size_t)LIST_CAP * 4;   // 33 MiB

  if (ws_size < NEED) {
    // cannot run selection; fail loudly via passthrough
    (void)hipMemcpyAsync(out, v, (size_t)E * 4, hipMemcpyDeviceToDevice, stream);
    return;
  }

  unsigned* state  = (unsigned*)(ws + STATE_OFF);
  unsigned* hist_s = (unsigned*)(ws + HISTS_OFF);
  unsigned* hist2  = (unsigned*)(ws + HIST2_OFF);
  uint2*    mini   = (uint2*)(ws + MINI_OFF);
  unsigned* bh2    = (unsigned*)(ws + BH2_OFF);
  uint2*    list   = (uint2*)(ws + LIST_OFF);
  unsigned* elist  = (unsigned*)(ws + ELIST_OFF);

  int nvec = E >> 2;
  int chunk = (nvec + NBS - 1) / NBS;
  int spb = chunk < 256 ? chunk : 256;
  long long SN = (long long)NBS * (long long)spb * 4;

  (void)hipMemsetAsync(ws, 0, 40 * 1024, stream);   // state + hist_s

  sample_hist_kernel<<<NBS, 256, 0, stream>>>(v, dp, g, hist_s, nvec, chunk, spb);
  find_sample_kernel<<<1, 1024, 0, stream>>>(hist_s, state, pct, (long long)E, SN);
  stream_kernel<<<NBSTREAM, STREAM_T, 0, stream>>>(v, dp, g, out, state, list, E, 0);
  find_verify_kernel<<<1, 64, 0, stream>>>(state);
  stream_kernel<<<NBSTREAM, STREAM_T, 0, stream>>>(v, dp, g, out, state, list, E, 1);
  exact_eval_kernel<<<NB2, 256, 0, stream>>>(dp, g, list, elist, state, bh2);
  reduce_hist2_kernel<<<16, 256, 0, stream>>>(bh2, hist2);
  find_band_kernel<<<1, 1024, 0, stream>>>(hist2, state);
  band_drop_kernel<<<256, 256, 0, stream>>>(list, elist, state, out, mini);
  mini_ties_kernel<<<1, 1024, 0, stream>>>(mini, state, out);
}